// Round 7
// baseline (851.389 us; speedup 1.0000x reference)
//
#include <hip/hip_runtime.h>

#define N_NODES 200000
#define N_EDGES 6400000

constexpr int BSHIFT = 9;                      // 512 nodes per bucket
constexpr int NBUCK  = (N_NODES + 511) / 512;  // 391
constexpr int CHUNK  = 16384;
constexpr int NCHUNK = (N_EDGES + CHUNK - 1) / CHUNK;  // 391
constexpr int MAXBUCK = 18432;                 // lambda=16384, +16 sigma
constexpr int SEGSTRIDE = 2052;                // 2048 bins + end sentinel + pad

// ---- edge index load helper: handles int32 or int64 storage ----
__device__ __forceinline__ int ld_edge(const void* ei, int is64, int idx) {
    return is64 ? (int)((const long long*)ei)[idx] : ((const int*)ei)[idx];
}

__global__ void k_zero(int* __restrict__ p, int n) {
    int i = blockIdx.x * blockDim.x + threadIdx.x;
    if (i < n) p[i] = 0;
}

// int64 little-endian values < 2^31  =>  every odd u32 slot is 0
__global__ void k_detect(const unsigned int* __restrict__ ei, int* __restrict__ flag) {
    __shared__ int nz;
    if (threadIdx.x == 0) nz = 0;
    __syncthreads();
    if (ei[2 * threadIdx.x + 1] != 0u) atomicOr(&nz, 1);
    __syncthreads();
    if (threadIdx.x == 0) *flag = nz ? 0 : 1;
}

// bucket histogram: LDS-accumulated, one global atomic per bucket per block
__global__ void k_hist(const void* __restrict__ ei, const int* __restrict__ flag,
                       int* __restrict__ bucketCnt) {
    __shared__ int h[NBUCK];
    for (int i = threadIdx.x; i < NBUCK; i += 256) h[i] = 0;
    __syncthreads();
    const int is64 = *flag;
    int stride = gridDim.x * blockDim.x;
    for (int e = blockIdx.x * 256 + threadIdx.x; e < N_EDGES; e += stride) {
        int d = ld_edge(ei, is64, N_EDGES + e);
        atomicAdd(&h[d >> BSHIFT], 1);
    }
    __syncthreads();
    for (int i = threadIdx.x; i < NBUCK; i += 256)
        if (h[i]) atomicAdd(&bucketCnt[i], h[i]);
}

// single-block scan of 391 bucket counts -> exclusive bases + cursors
__global__ void k_scan_buckets(const int* __restrict__ bucketCnt,
                               int* __restrict__ bucketBase,
                               int* __restrict__ bucketCursor) {
    __shared__ int sc[512];
    int t = threadIdx.x;
    sc[t]       = (t < NBUCK)       ? bucketCnt[t]       : 0;
    sc[t + 256] = (t + 256 < NBUCK) ? bucketCnt[t + 256] : 0;
    __syncthreads();
    for (int off = 1; off < 512; off <<= 1) {
        int a0 = (t >= off) ? sc[t - off] : 0;
        int a1 = sc[t + 256 - off];
        __syncthreads();
        sc[t] += a0; sc[t + 256] += a1;
        __syncthreads();
    }
    for (int i = t; i < NBUCK; i += 256) {
        int excl = sc[i] - bucketCnt[i];
        bucketBase[i] = excl;
        bucketCursor[i] = excl;
    }
    if (t == 0) bucketBase[NBUCK] = N_EDGES;
}

// level-1: bin a 16K-edge chunk by bucket in LDS, write contiguous runs
__global__ void __launch_bounds__(256)
k_binscatter(const void* __restrict__ ei, const int* __restrict__ flag,
             int* __restrict__ bucketCursor, unsigned int* __restrict__ bin) {
    __shared__ int hist[NBUCK];
    __shared__ int pref[NBUCK + 1];
    __shared__ int cur[NBUCK];
    __shared__ int gb[NBUCK];
    __shared__ int sc[512];
    __shared__ unsigned int stage[CHUNK];
    const int is64 = *flag;
    int b = blockIdx.x, t = threadIdx.x;
    int e0 = b * CHUNK;
    int n = min(CHUNK, N_EDGES - e0);
    for (int i = t; i < NBUCK; i += 256) hist[i] = 0;
    __syncthreads();
    for (int i = t; i < n; i += 256) {
        int d = ld_edge(ei, is64, N_EDGES + e0 + i);
        atomicAdd(&hist[d >> BSHIFT], 1);
    }
    __syncthreads();
    sc[t]       = (t < NBUCK)       ? hist[t]       : 0;
    sc[t + 256] = (t + 256 < NBUCK) ? hist[t + 256] : 0;
    __syncthreads();
    for (int off = 1; off < 512; off <<= 1) {
        int a0 = (t >= off) ? sc[t - off] : 0;
        int a1 = sc[t + 256 - off];
        __syncthreads();
        sc[t] += a0; sc[t + 256] += a1;
        __syncthreads();
    }
    for (int i = t; i < NBUCK; i += 256) {
        int excl = sc[i] - hist[i];
        pref[i] = excl;
        cur[i] = excl;
    }
    if (t == 0) pref[NBUCK] = n;
    __syncthreads();
    for (int i = t; i < n; i += 256) {
        int s = ld_edge(ei, is64, e0 + i);
        int d = ld_edge(ei, is64, N_EDGES + e0 + i);
        int bk = d >> BSHIFT;
        int p = atomicAdd(&cur[bk], 1);
        stage[p] = ((unsigned int)(d & 511) << 18) | (unsigned int)s;
    }
    __syncthreads();
    for (int i = t; i < NBUCK; i += 256) {
        int c = hist[i];
        gb[i] = c ? atomicAdd(&bucketCursor[i], c) : 0;
    }
    __syncthreads();
    for (int p = t; p < n; p += 256) {
        int lo = 0, hi = NBUCK;
        while (hi - lo > 1) {
            int mid = (lo + hi) >> 1;
            if (pref[mid] <= p) lo = mid; else hi = mid;
        }
        bin[gb[lo] + (p - pref[lo])] = stage[p];
    }
}

// level-2: one block per bucket. Counting-sort the bucket's edges by key
// (q<<9)|local_dst (q = src/50000), emit per-(q,dst) u16 rowptr + dinv.
__global__ void __launch_bounds__(256)
k_bucketsort(const int* __restrict__ bucketBase, unsigned int* __restrict__ bin,
             float* __restrict__ dinv, unsigned short* __restrict__ seg16) {
    __shared__ int cnt[2048];
    __shared__ int cur[2048];
    __shared__ int tsum[256];
    __shared__ unsigned int payload[MAXBUCK];
    int b = blockIdx.x, t = threadIdx.x;
    int base = bucketBase[b], end = bucketBase[b + 1];
    int n = end - base;
    for (int i = t; i < 2048; i += 256) cnt[i] = 0;
    __syncthreads();
    // pass A: histogram over 2048 (q, local_dst) bins
    for (int i = t; i < n; i += 256) {
        unsigned int u = bin[base + i];
        int src = (int)(u & 0x3FFFFu);
        int key = ((src / 50000) << 9) | (int)(u >> 18);
        atomicAdd(&cnt[key], 1);
    }
    __syncthreads();
    // scan 2048: serial-8 per thread + Hillis-Steele over 256 thread sums
    int b0 = t * 8;
    int s = 0;
#pragma unroll
    for (int j = 0; j < 8; ++j) s += cnt[b0 + j];
    tsum[t] = s;
    __syncthreads();
    int v = s;
    for (int off = 1; off < 256; off <<= 1) {
        int add = (t >= off) ? tsum[t - off] : 0;
        __syncthreads();
        tsum[t] += add;
        __syncthreads();
    }
    int run = tsum[t] - v;  // exclusive prefix of this thread's chunk
#pragma unroll
    for (int j = 0; j < 8; ++j) { cur[b0 + j] = run; run += cnt[b0 + j]; }
    __syncthreads();
    // write u16 relative rowptr (before scatter mutates cur) + sentinel + dinv
    for (int i = t; i < 2048; i += 256)
        seg16[b * SEGSTRIDE + i] = (unsigned short)cur[i];
    if (t == 0) seg16[b * SEGSTRIDE + 2048] = (unsigned short)n;
    int node0 = b << BSHIFT;
    for (int d = t; d < 512; d += 256) {
        int node = node0 + d;
        if (node < N_NODES) {
            int deg = cnt[d] + cnt[512 + d] + cnt[1024 + d] + cnt[1536 + d];
            dinv[node] = rsqrtf((float)deg + 1.0f);
        }
    }
    __syncthreads();
    // pass B: scatter into payload by final position
    for (int i = t; i < n; i += 256) {
        unsigned int u = bin[base + i];
        int src = (int)(u & 0x3FFFFu);
        int key = ((src / 50000) << 9) | (int)(u >> 18);
        int p = atomicAdd(&cur[key], 1);
        if (p < MAXBUCK) payload[p] = u;
    }
    __syncthreads();
    // coalesced in-place write-back (sorted by (q, local_dst))
    for (int i = t; i < n; i += 256) bin[base + i] = payload[i];
}

// hs = dinv[i] * (x @ W), padded to stride 16 (one 64B line per row).
template <int FIN, int FOUT, int SIN>
__global__ void k_xw(const float* xin, const float* __restrict__ W,
                     const float* __restrict__ dinv, float* hs) {
    __shared__ float sW[FIN * FOUT];
    int t = threadIdx.x;
    if (t < FIN * FOUT) sW[t] = W[t];
    __syncthreads();
    int i = blockIdx.x * 256 + t;
    if (i >= N_NODES) return;
    float xi[FIN];
#pragma unroll
    for (int k = 0; k < FIN; ++k) xi[k] = xin[i * SIN + k];
    float di = dinv[i];
    float o[FOUT];
#pragma unroll
    for (int j = 0; j < FOUT; ++j) {
        float acc = 0.f;
#pragma unroll
        for (int k = 0; k < FIN; ++k) acc += xi[k] * sW[k * FOUT + j];
        o[j] = di * acc;
    }
#pragma unroll
    for (int j = 0; j < FOUT; ++j) hs[i * 16 + j] = o[j];
}

// Fused boundary kernel: x' = relu(dinv*(accG + hs_prev) + biasPrev);
// hs_next = dinv * (x' @ Wnext) -> B.
template <int FIN, int FOUT>
__global__ void k_fx(float* __restrict__ B, const float* __restrict__ accG,
                     const float* __restrict__ dinv,
                     const float* __restrict__ biasPrev,
                     const float* __restrict__ Wnext) {
    __shared__ float sW[FIN * FOUT];
    __shared__ float sb[FIN];
    int t = threadIdx.x;
    if (t < FIN * FOUT) sW[t] = Wnext[t];
    if (t < FIN) sb[t] = biasPrev[t];
    __syncthreads();
    int i = blockIdx.x * 256 + t;
    if (i >= N_NODES) return;
    float di = dinv[i];
    float xi[FIN];
#pragma unroll
    for (int k = 0; k < FIN; ++k) {
        float v = di * (accG[i * 16 + k] + B[i * 16 + k]) + sb[k];
        xi[k] = fmaxf(v, 0.f);
    }
    float o[FOUT];
#pragma unroll
    for (int j = 0; j < FOUT; ++j) {
        float acc = 0.f;
#pragma unroll
        for (int k = 0; k < FIN; ++k) acc += xi[k] * sW[k * FOUT + j];
        o[j] = di * acc;
    }
#pragma unroll
    for (int j = 0; j < FOUT; ++j) B[i * 16 + j] = o[j];
}

// One block per (bucket, quarter). 32 groups x 16 lanes (lane = feature);
// each group owns 4 consecutive dsts. q-segments walked SERIALLY (keeps the
// 3.2 MB per-q gather window L2-warm) while the 4 dst-runs are walked
// CONCURRENTLY as 4 independent register chains (MLP). Epilogue: one plain
// coalesced 64 B store per dst -- NO atomics anywhere.
__global__ void __launch_bounds__(512)
k_agg(const int* __restrict__ bucketBase, const unsigned short* __restrict__ seg16,
      const unsigned int* __restrict__ bin, const float* __restrict__ hs,
      float* __restrict__ accG) {
    __shared__ unsigned short s_sr[4 * 132];
    int blk = blockIdx.x;
    int Q = blk & 3;
    int b = blk >> 2;
    int t = threadIdx.x;
    int base = bucketBase[b];
    const unsigned short* sr = seg16 + b * SEGSTRIDE + (Q << 7);
    if (t < 129) {
#pragma unroll
        for (int q = 0; q < 4; ++q) s_sr[q * 132 + t] = sr[(q << 9) + t];
    }
    __syncthreads();
    int g = t >> 4, f = t & 15;
    int dd0 = g << 2;
    float a0 = 0.f, a1 = 0.f, a2 = 0.f, a3 = 0.f;
#pragma unroll 1
    for (int q = 0; q < 4; ++q) {
        const unsigned short* sq = &s_sr[q * 132 + dd0];
        int r0 = (int)sq[0], r1 = (int)sq[1], r2 = (int)sq[2];
        int r3 = (int)sq[3], r4 = (int)sq[4];
        int n0 = r1 - r0, n1 = r2 - r1, n2 = r3 - r2, n3 = r4 - r3;
        int e0 = base + r0, e1 = base + r1, e2 = base + r2, e3 = base + r3;
        int m = max(max(n0, n1), max(n2, n3));
#pragma unroll 1
        for (int k = 0; k < m; ++k) {
            if (k < n0) a0 += hs[((bin[e0 + k] & 0x3FFFFu) << 4) + f];
            if (k < n1) a1 += hs[((bin[e1 + k] & 0x3FFFFu) << 4) + f];
            if (k < n2) a2 += hs[((bin[e2 + k] & 0x3FFFFu) << 4) + f];
            if (k < n3) a3 += hs[((bin[e3 + k] & 0x3FFFFu) << 4) + f];
        }
    }
    int node0 = (b << BSHIFT) + (Q << 7) + dd0;
    if (node0 + 0 < N_NODES) accG[((node0 + 0) << 4) + f] = a0;
    if (node0 + 1 < N_NODES) accG[((node0 + 1) << 4) + f] = a1;
    if (node0 + 2 < N_NODES) accG[((node0 + 2) << 4) + f] = a2;
    if (node0 + 3 < N_NODES) accG[((node0 + 3) << 4) + f] = a3;
}

// out = dinv*(accG + hs_self) + bias, in place (accG aliases d_out).
template <int F, bool RELU>
__global__ void k_finish(float* __restrict__ B, float* __restrict__ accG,
                         const float* __restrict__ dinv,
                         const float* __restrict__ bias, float* __restrict__ out) {
    int i = blockIdx.x * blockDim.x + threadIdx.x;
    if (i >= N_NODES * 16) return;
    int node = i >> 4, ff = i & 15;
    float di = dinv[node];
    if (ff < F) {
        float r = di * (accG[i] + B[i]) + bias[ff];
        if (RELU) r = fmaxf(r, 0.f);
        out[node * 16 + ff] = r;
    }
}

extern "C" void kernel_launch(void* const* d_in, const int* in_sizes, int n_in,
                              void* d_out, int out_size, void* d_ws, size_t ws_size,
                              hipStream_t stream) {
    const float* x  = (const float*)d_in[0];
    const void*  ei = d_in[1];
    const float* W1 = (const float*)d_in[2];
    const float* b1 = (const float*)d_in[3];
    const float* W2 = (const float*)d_in[4];
    const float* b2 = (const float*)d_in[5];
    const float* W3 = (const float*)d_in[6];
    const float* b3 = (const float*)d_in[7];
    float* out = (float*)d_out;

    char* w = (char*)d_ws;
    int*   bucketCnt    = (int*)(w + 0);        //    2048 B (512 ints, zeroed)
    int*   bucketBase   = (int*)(w + 2048);     //    2048 B
    int*   bucketCursor = (int*)(w + 4096);     //    2048 B
    int*   flag         = (int*)(w + 6144);     //      64 B
    float* dinv         = (float*)(w + 6208);   //  800000 B
    unsigned short* seg16 = (unsigned short*)(w + 806208); // 391*2052*2 = 1604664 B
    unsigned int* bin   = (unsigned int*)(w + 2410880);    // 25600000 B
    float* B            = (float*)(w + 28010880);          // 12800000 B (N*16)
    float* accG         = out;                  // d_out doubles as accumulator
    // total ws use ~40.8 MB

    // ---- build (q,dst)-sorted bucketed edges (no accG zeroing needed) ----
    k_zero<<<2, 256, 0, stream>>>(bucketCnt, 512);
    k_detect<<<1, 256, 0, stream>>>((const unsigned int*)ei, flag);
    k_hist<<<1024, 256, 0, stream>>>(ei, flag, bucketCnt);
    k_scan_buckets<<<1, 256, 0, stream>>>(bucketCnt, bucketBase, bucketCursor);
    k_binscatter<<<NCHUNK, 256, 0, stream>>>(ei, flag, bucketCursor, bin);
    k_bucketsort<<<NBUCK, 256, 0, stream>>>(bucketBase, bin, dinv, seg16);

    // ---- layer 1 ----
    k_xw<11, 11, 11><<<782, 256, 0, stream>>>(x, W1, dinv, B);
    k_agg<<<NBUCK * 4, 512, 0, stream>>>(bucketBase, seg16, bin, B, accG);
    // ---- boundary 1: finish L1 + xw L2 ----
    k_fx<11, 11><<<782, 256, 0, stream>>>(B, accG, dinv, b1, W2);
    // ---- layer 2 ----
    k_agg<<<NBUCK * 4, 512, 0, stream>>>(bucketBase, seg16, bin, B, accG);
    // ---- boundary 2: finish L2 + xw L3 ----
    k_fx<11, 16><<<782, 256, 0, stream>>>(B, accG, dinv, b2, W3);
    // ---- layer 3 ----
    k_agg<<<NBUCK * 4, 512, 0, stream>>>(bucketBase, seg16, bin, B, accG);
    k_finish<16, false><<<12500, 256, 0, stream>>>(B, accG, dinv, b3, out);
}

// Round 8
// 676.329 us; speedup vs baseline: 1.2588x; 1.2588x over previous
//
#include <hip/hip_runtime.h>

#define N_NODES 200000
#define N_EDGES 6400000

constexpr int BSHIFT = 9;                      // 512 nodes per bucket
constexpr int NBUCK  = (N_NODES + 511) / 512;  // 391
constexpr int CHUNK  = 16384;
constexpr int NCHUNK = (N_EDGES + CHUNK - 1) / CHUNK;  // 391
constexpr int MAXBUCK = 18432;                 // lambda=16384, +16 sigma
constexpr int SEGSTRIDE = 2052;                // 2048 bins + end sentinel + pad

// ---- edge index load helper: handles int32 or int64 storage ----
__device__ __forceinline__ int ld_edge(const void* ei, int is64, int idx) {
    return is64 ? (int)((const long long*)ei)[idx] : ((const int*)ei)[idx];
}

__global__ void k_zero(int* __restrict__ p, int n) {
    int i = blockIdx.x * blockDim.x + threadIdx.x;
    if (i < n) p[i] = 0;
}

// int64 little-endian values < 2^31  =>  every odd u32 slot is 0
__global__ void k_detect(const unsigned int* __restrict__ ei, int* __restrict__ flag) {
    __shared__ int nz;
    if (threadIdx.x == 0) nz = 0;
    __syncthreads();
    if (ei[2 * threadIdx.x + 1] != 0u) atomicOr(&nz, 1);
    __syncthreads();
    if (threadIdx.x == 0) *flag = nz ? 0 : 1;
}

// bucket histogram: LDS-accumulated, one global atomic per bucket per block
__global__ void k_hist(const void* __restrict__ ei, const int* __restrict__ flag,
                       int* __restrict__ bucketCnt) {
    __shared__ int h[NBUCK];
    for (int i = threadIdx.x; i < NBUCK; i += 256) h[i] = 0;
    __syncthreads();
    const int is64 = *flag;
    int stride = gridDim.x * blockDim.x;
    for (int e = blockIdx.x * 256 + threadIdx.x; e < N_EDGES; e += stride) {
        int d = ld_edge(ei, is64, N_EDGES + e);
        atomicAdd(&h[d >> BSHIFT], 1);
    }
    __syncthreads();
    for (int i = threadIdx.x; i < NBUCK; i += 256)
        if (h[i]) atomicAdd(&bucketCnt[i], h[i]);
}

// single-block scan of 391 bucket counts -> exclusive bases + cursors
__global__ void k_scan_buckets(const int* __restrict__ bucketCnt,
                               int* __restrict__ bucketBase,
                               int* __restrict__ bucketCursor) {
    __shared__ int sc[512];
    int t = threadIdx.x;
    sc[t]       = (t < NBUCK)       ? bucketCnt[t]       : 0;
    sc[t + 256] = (t + 256 < NBUCK) ? bucketCnt[t + 256] : 0;
    __syncthreads();
    for (int off = 1; off < 512; off <<= 1) {
        int a0 = (t >= off) ? sc[t - off] : 0;
        int a1 = sc[t + 256 - off];
        __syncthreads();
        sc[t] += a0; sc[t + 256] += a1;
        __syncthreads();
    }
    for (int i = t; i < NBUCK; i += 256) {
        int excl = sc[i] - bucketCnt[i];
        bucketBase[i] = excl;
        bucketCursor[i] = excl;
    }
    if (t == 0) bucketBase[NBUCK] = N_EDGES;
}

// level-1: bin a 16K-edge chunk by bucket in LDS, write contiguous runs
__global__ void __launch_bounds__(256)
k_binscatter(const void* __restrict__ ei, const int* __restrict__ flag,
             int* __restrict__ bucketCursor, unsigned int* __restrict__ bin) {
    __shared__ int hist[NBUCK];
    __shared__ int pref[NBUCK + 1];
    __shared__ int cur[NBUCK];
    __shared__ int gb[NBUCK];
    __shared__ int sc[512];
    __shared__ unsigned int stage[CHUNK];
    const int is64 = *flag;
    int b = blockIdx.x, t = threadIdx.x;
    int e0 = b * CHUNK;
    int n = min(CHUNK, N_EDGES - e0);
    for (int i = t; i < NBUCK; i += 256) hist[i] = 0;
    __syncthreads();
    for (int i = t; i < n; i += 256) {
        int d = ld_edge(ei, is64, N_EDGES + e0 + i);
        atomicAdd(&hist[d >> BSHIFT], 1);
    }
    __syncthreads();
    sc[t]       = (t < NBUCK)       ? hist[t]       : 0;
    sc[t + 256] = (t + 256 < NBUCK) ? hist[t + 256] : 0;
    __syncthreads();
    for (int off = 1; off < 512; off <<= 1) {
        int a0 = (t >= off) ? sc[t - off] : 0;
        int a1 = sc[t + 256 - off];
        __syncthreads();
        sc[t] += a0; sc[t + 256] += a1;
        __syncthreads();
    }
    for (int i = t; i < NBUCK; i += 256) {
        int excl = sc[i] - hist[i];
        pref[i] = excl;
        cur[i] = excl;
    }
    if (t == 0) pref[NBUCK] = n;
    __syncthreads();
    for (int i = t; i < n; i += 256) {
        int s = ld_edge(ei, is64, e0 + i);
        int d = ld_edge(ei, is64, N_EDGES + e0 + i);
        int bk = d >> BSHIFT;
        int p = atomicAdd(&cur[bk], 1);
        stage[p] = ((unsigned int)(d & 511) << 18) | (unsigned int)s;
    }
    __syncthreads();
    for (int i = t; i < NBUCK; i += 256) {
        int c = hist[i];
        gb[i] = c ? atomicAdd(&bucketCursor[i], c) : 0;
    }
    __syncthreads();
    for (int p = t; p < n; p += 256) {
        int lo = 0, hi = NBUCK;
        while (hi - lo > 1) {
            int mid = (lo + hi) >> 1;
            if (pref[mid] <= p) lo = mid; else hi = mid;
        }
        bin[gb[lo] + (p - pref[lo])] = stage[p];
    }
}

// level-2: one block per bucket. Counting-sort the bucket's edges by key
// (q<<9)|local_dst (q = src/50000), emit per-(q,dst) u16 rowptr + dinv.
__global__ void __launch_bounds__(256)
k_bucketsort(const int* __restrict__ bucketBase, unsigned int* __restrict__ bin,
             float* __restrict__ dinv, unsigned short* __restrict__ seg16) {
    __shared__ int cnt[2048];
    __shared__ int cur[2048];
    __shared__ int tsum[256];
    __shared__ unsigned int payload[MAXBUCK];
    int b = blockIdx.x, t = threadIdx.x;
    int base = bucketBase[b], end = bucketBase[b + 1];
    int n = end - base;
    for (int i = t; i < 2048; i += 256) cnt[i] = 0;
    __syncthreads();
    // pass A: histogram over 2048 (q, local_dst) bins
    for (int i = t; i < n; i += 256) {
        unsigned int u = bin[base + i];
        int src = (int)(u & 0x3FFFFu);
        int key = ((src / 50000) << 9) | (int)(u >> 18);
        atomicAdd(&cnt[key], 1);
    }
    __syncthreads();
    // scan 2048: serial-8 per thread + Hillis-Steele over 256 thread sums
    int b0 = t * 8;
    int s = 0;
#pragma unroll
    for (int j = 0; j < 8; ++j) s += cnt[b0 + j];
    tsum[t] = s;
    __syncthreads();
    int v = s;
    for (int off = 1; off < 256; off <<= 1) {
        int add = (t >= off) ? tsum[t - off] : 0;
        __syncthreads();
        tsum[t] += add;
        __syncthreads();
    }
    int run = tsum[t] - v;  // exclusive prefix of this thread's chunk
#pragma unroll
    for (int j = 0; j < 8; ++j) { cur[b0 + j] = run; run += cnt[b0 + j]; }
    __syncthreads();
    // write u16 relative rowptr (before scatter mutates cur) + sentinel + dinv
    for (int i = t; i < 2048; i += 256)
        seg16[b * SEGSTRIDE + i] = (unsigned short)cur[i];
    if (t == 0) seg16[b * SEGSTRIDE + 2048] = (unsigned short)n;
    int node0 = b << BSHIFT;
    for (int d = t; d < 512; d += 256) {
        int node = node0 + d;
        if (node < N_NODES) {
            int deg = cnt[d] + cnt[512 + d] + cnt[1024 + d] + cnt[1536 + d];
            dinv[node] = rsqrtf((float)deg + 1.0f);
        }
    }
    __syncthreads();
    // pass B: scatter into payload by final position
    for (int i = t; i < n; i += 256) {
        unsigned int u = bin[base + i];
        int src = (int)(u & 0x3FFFFu);
        int key = ((src / 50000) << 9) | (int)(u >> 18);
        int p = atomicAdd(&cur[key], 1);
        if (p < MAXBUCK) payload[p] = u;
    }
    __syncthreads();
    // coalesced in-place write-back (sorted by (q, local_dst))
    for (int i = t; i < n; i += 256) bin[base + i] = payload[i];
}

// hs = dinv[i] * (x @ W), padded to stride 16 (one 64B line per row).
template <int FIN, int FOUT, int SIN>
__global__ void k_xw(const float* xin, const float* __restrict__ W,
                     const float* __restrict__ dinv, float* hs) {
    __shared__ float sW[FIN * FOUT];
    int t = threadIdx.x;
    if (t < FIN * FOUT) sW[t] = W[t];
    __syncthreads();
    int i = blockIdx.x * 256 + t;
    if (i >= N_NODES) return;
    float xi[FIN];
#pragma unroll
    for (int k = 0; k < FIN; ++k) xi[k] = xin[i * SIN + k];
    float di = dinv[i];
    float o[FOUT];
#pragma unroll
    for (int j = 0; j < FOUT; ++j) {
        float acc = 0.f;
#pragma unroll
        for (int k = 0; k < FIN; ++k) acc += xi[k] * sW[k * FOUT + j];
        o[j] = di * acc;
    }
#pragma unroll
    for (int j = 0; j < FOUT; ++j) hs[i * 16 + j] = o[j];
}

// Fused boundary kernel: x' = relu(dinv*(accG + hs_prev) + biasPrev);
// hs_next = dinv * (x' @ Wnext) -> B. Re-zeros accG for the next layer.
template <int FIN, int FOUT>
__global__ void k_fx(float* __restrict__ B, float* __restrict__ accG,
                     const float* __restrict__ dinv,
                     const float* __restrict__ biasPrev,
                     const float* __restrict__ Wnext) {
    __shared__ float sW[FIN * FOUT];
    __shared__ float sb[FIN];
    int t = threadIdx.x;
    if (t < FIN * FOUT) sW[t] = Wnext[t];
    if (t < FIN) sb[t] = biasPrev[t];
    __syncthreads();
    int i = blockIdx.x * 256 + t;
    if (i >= N_NODES) return;
    float di = dinv[i];
    float xi[FIN];
#pragma unroll
    for (int k = 0; k < FIN; ++k) {
        float v = di * (accG[i * 16 + k] + B[i * 16 + k]) + sb[k];
        xi[k] = fmaxf(v, 0.f);
    }
#pragma unroll
    for (int c = 0; c < 16; ++c) accG[i * 16 + c] = 0.f;
    float o[FOUT];
#pragma unroll
    for (int j = 0; j < FOUT; ++j) {
        float acc = 0.f;
#pragma unroll
        for (int k = 0; k < FIN; ++k) acc += xi[k] * sW[k * FOUT + j];
        o[j] = di * acc;
    }
#pragma unroll
    for (int j = 0; j < FOUT; ++j) B[i * 16 + j] = o[j];
}

// One block per (bucket, quarter, q). q = blk&3 -> XCD-pinned 3.2 MB src
// window (L2-resident gathers, proven FETCH ~30 MB in R6). 32 groups x 16
// lanes (lane = feature); each group owns 4 consecutive dsts walked as 4
// CONCURRENT register chains, unroll-2 => ~8 independent hs loads in flight.
// Flush: one unsafeAtomicAdd per (dst,f) with 16 consecutive lanes -> single
// 64 B line RMW (proven WRITE = exact payload in R5).
__global__ void __launch_bounds__(512)
k_agg(const int* __restrict__ bucketBase, const unsigned short* __restrict__ seg16,
      const unsigned int* __restrict__ bin, const float* __restrict__ hs,
      float* __restrict__ accG) {
    __shared__ unsigned short s_sr[132];
    int blk = blockIdx.x;
    int q = blk & 3;
    int Q = (blk >> 2) & 3;
    int b = blk >> 4;
    int t = threadIdx.x;
    int base = bucketBase[b];
    const unsigned short* sr = seg16 + b * SEGSTRIDE + (q << 9) + (Q << 7);
    if (t < 129) s_sr[t] = sr[t];
    __syncthreads();
    int g = t >> 4, f = t & 15;
    int dd0 = g << 2;
    int r0 = (int)s_sr[dd0 + 0], r1 = (int)s_sr[dd0 + 1], r2 = (int)s_sr[dd0 + 2];
    int r3 = (int)s_sr[dd0 + 3], r4 = (int)s_sr[dd0 + 4];
    int n0 = r1 - r0, n1 = r2 - r1, n2 = r3 - r2, n3 = r4 - r3;
    const unsigned int* p0 = bin + base + r0;
    const unsigned int* p1 = bin + base + r1;
    const unsigned int* p2 = bin + base + r2;
    const unsigned int* p3 = bin + base + r3;
    float a0 = 0.f, a1 = 0.f, a2 = 0.f, a3 = 0.f;
    int m = max(max(n0, n1), max(n2, n3));
#pragma unroll 2
    for (int k = 0; k < m; ++k) {
        if (k < n0) a0 += hs[((p0[k] & 0x3FFFFu) << 4) + f];
        if (k < n1) a1 += hs[((p1[k] & 0x3FFFFu) << 4) + f];
        if (k < n2) a2 += hs[((p2[k] & 0x3FFFFu) << 4) + f];
        if (k < n3) a3 += hs[((p3[k] & 0x3FFFFu) << 4) + f];
    }
    int node0 = (b << BSHIFT) + (Q << 7) + dd0;
    if (node0 + 0 < N_NODES) unsafeAtomicAdd(&accG[((node0 + 0) << 4) + f], a0);
    if (node0 + 1 < N_NODES) unsafeAtomicAdd(&accG[((node0 + 1) << 4) + f], a1);
    if (node0 + 2 < N_NODES) unsafeAtomicAdd(&accG[((node0 + 2) << 4) + f], a2);
    if (node0 + 3 < N_NODES) unsafeAtomicAdd(&accG[((node0 + 3) << 4) + f], a3);
}

// out = dinv*(accG + hs_self) + bias, in place (accG aliases d_out).
template <int F, bool RELU>
__global__ void k_finish(float* __restrict__ B, float* __restrict__ accG,
                         const float* __restrict__ dinv,
                         const float* __restrict__ bias, float* __restrict__ out) {
    int i = blockIdx.x * blockDim.x + threadIdx.x;
    if (i >= N_NODES * 16) return;
    int node = i >> 4, ff = i & 15;
    float di = dinv[node];
    if (ff < F) {
        float r = di * (accG[i] + B[i]) + bias[ff];
        if (RELU) r = fmaxf(r, 0.f);
        out[node * 16 + ff] = r;
    }
}

extern "C" void kernel_launch(void* const* d_in, const int* in_sizes, int n_in,
                              void* d_out, int out_size, void* d_ws, size_t ws_size,
                              hipStream_t stream) {
    const float* x  = (const float*)d_in[0];
    const void*  ei = d_in[1];
    const float* W1 = (const float*)d_in[2];
    const float* b1 = (const float*)d_in[3];
    const float* W2 = (const float*)d_in[4];
    const float* b2 = (const float*)d_in[5];
    const float* W3 = (const float*)d_in[6];
    const float* b3 = (const float*)d_in[7];
    float* out = (float*)d_out;

    char* w = (char*)d_ws;
    int*   bucketCnt    = (int*)(w + 0);        //    2048 B (512 ints, zeroed)
    int*   bucketBase   = (int*)(w + 2048);     //    2048 B
    int*   bucketCursor = (int*)(w + 4096);     //    2048 B
    int*   flag         = (int*)(w + 6144);     //      64 B
    float* dinv         = (float*)(w + 6208);   //  800000 B
    unsigned short* seg16 = (unsigned short*)(w + 806208); // 391*2052*2 = 1604664 B
    unsigned int* bin   = (unsigned int*)(w + 2410880);    // 25600000 B
    float* B            = (float*)(w + 28010880);          // 12800000 B (N*16)
    float* accG         = out;                  // d_out doubles as accumulator
    // total ws use ~40.8 MB

    // ---- zero accumulator + build (q,dst)-sorted bucketed edges ----
    k_zero<<<12500, 256, 0, stream>>>((int*)accG, N_NODES * 16);
    k_zero<<<2, 256, 0, stream>>>(bucketCnt, 512);
    k_detect<<<1, 256, 0, stream>>>((const unsigned int*)ei, flag);
    k_hist<<<1024, 256, 0, stream>>>(ei, flag, bucketCnt);
    k_scan_buckets<<<1, 256, 0, stream>>>(bucketCnt, bucketBase, bucketCursor);
    k_binscatter<<<NCHUNK, 256, 0, stream>>>(ei, flag, bucketCursor, bin);
    k_bucketsort<<<NBUCK, 256, 0, stream>>>(bucketBase, bin, dinv, seg16);

    // ---- layer 1 ----
    k_xw<11, 11, 11><<<782, 256, 0, stream>>>(x, W1, dinv, B);
    k_agg<<<NBUCK * 16, 512, 0, stream>>>(bucketBase, seg16, bin, B, accG);
    // ---- boundary 1: finish L1 + xw L2 (re-zeros accG) ----
    k_fx<11, 11><<<782, 256, 0, stream>>>(B, accG, dinv, b1, W2);
    // ---- layer 2 ----
    k_agg<<<NBUCK * 16, 512, 0, stream>>>(bucketBase, seg16, bin, B, accG);
    // ---- boundary 2: finish L2 + xw L3 (re-zeros accG) ----
    k_fx<11, 16><<<782, 256, 0, stream>>>(B, accG, dinv, b2, W3);
    // ---- layer 3 ----
    k_agg<<<NBUCK * 16, 512, 0, stream>>>(bucketBase, seg16, bin, B, accG);
    k_finish<16, false><<<12500, 256, 0, stream>>>(B, accG, dinv, b3, out);
}

// Round 9
// 426.748 us; speedup vs baseline: 1.9951x; 1.5848x over previous
//
#include <hip/hip_runtime.h>

#define N_NODES 200000
#define N_EDGES 6400000

constexpr int BSHIFT = 9;                      // 512 nodes per bucket
constexpr int NBUCK  = (N_NODES + 511) / 512;  // 391
constexpr int CHUNK  = 16384;
constexpr int NCHUNK = (N_EDGES + CHUNK - 1) / CHUNK;  // 391
constexpr int MAXBUCK = 18432;                 // lambda=16384, +16 sigma
constexpr int SEGSTRIDE = 2052;                // 2048 bins + end sentinel + pad
constexpr int SEGMAX = 1536;                   // staged edges per (b,Q,q); lambda=1024

// ---- edge index load helper: handles int32 or int64 storage ----
__device__ __forceinline__ int ld_edge(const void* ei, int is64, int idx) {
    return is64 ? (int)((const long long*)ei)[idx] : ((const int*)ei)[idx];
}

__global__ void k_zero(int* __restrict__ p, int n) {
    int i = blockIdx.x * blockDim.x + threadIdx.x;
    if (i < n) p[i] = 0;
}

// int64 little-endian values < 2^31  =>  every odd u32 slot is 0
__global__ void k_detect(const unsigned int* __restrict__ ei, int* __restrict__ flag) {
    __shared__ int nz;
    if (threadIdx.x == 0) nz = 0;
    __syncthreads();
    if (ei[2 * threadIdx.x + 1] != 0u) atomicOr(&nz, 1);
    __syncthreads();
    if (threadIdx.x == 0) *flag = nz ? 0 : 1;
}

// bucket histogram: LDS-accumulated, one global atomic per bucket per block
__global__ void k_hist(const void* __restrict__ ei, const int* __restrict__ flag,
                       int* __restrict__ bucketCnt) {
    __shared__ int h[NBUCK];
    for (int i = threadIdx.x; i < NBUCK; i += 256) h[i] = 0;
    __syncthreads();
    const int is64 = *flag;
    int stride = gridDim.x * blockDim.x;
    for (int e = blockIdx.x * 256 + threadIdx.x; e < N_EDGES; e += stride) {
        int d = ld_edge(ei, is64, N_EDGES + e);
        atomicAdd(&h[d >> BSHIFT], 1);
    }
    __syncthreads();
    for (int i = threadIdx.x; i < NBUCK; i += 256)
        if (h[i]) atomicAdd(&bucketCnt[i], h[i]);
}

// single-block scan of 391 bucket counts -> exclusive bases + cursors
__global__ void k_scan_buckets(const int* __restrict__ bucketCnt,
                               int* __restrict__ bucketBase,
                               int* __restrict__ bucketCursor) {
    __shared__ int sc[512];
    int t = threadIdx.x;
    sc[t]       = (t < NBUCK)       ? bucketCnt[t]       : 0;
    sc[t + 256] = (t + 256 < NBUCK) ? bucketCnt[t + 256] : 0;
    __syncthreads();
    for (int off = 1; off < 512; off <<= 1) {
        int a0 = (t >= off) ? sc[t - off] : 0;
        int a1 = sc[t + 256 - off];
        __syncthreads();
        sc[t] += a0; sc[t + 256] += a1;
        __syncthreads();
    }
    for (int i = t; i < NBUCK; i += 256) {
        int excl = sc[i] - bucketCnt[i];
        bucketBase[i] = excl;
        bucketCursor[i] = excl;
    }
    if (t == 0) bucketBase[NBUCK] = N_EDGES;
}

// level-1: bin a 16K-edge chunk by bucket in LDS, write contiguous runs
__global__ void __launch_bounds__(256)
k_binscatter(const void* __restrict__ ei, const int* __restrict__ flag,
             int* __restrict__ bucketCursor, unsigned int* __restrict__ bin) {
    __shared__ int hist[NBUCK];
    __shared__ int pref[NBUCK + 1];
    __shared__ int cur[NBUCK];
    __shared__ int gb[NBUCK];
    __shared__ int sc[512];
    __shared__ unsigned int stage[CHUNK];
    const int is64 = *flag;
    int b = blockIdx.x, t = threadIdx.x;
    int e0 = b * CHUNK;
    int n = min(CHUNK, N_EDGES - e0);
    for (int i = t; i < NBUCK; i += 256) hist[i] = 0;
    __syncthreads();
    for (int i = t; i < n; i += 256) {
        int d = ld_edge(ei, is64, N_EDGES + e0 + i);
        atomicAdd(&hist[d >> BSHIFT], 1);
    }
    __syncthreads();
    sc[t]       = (t < NBUCK)       ? hist[t]       : 0;
    sc[t + 256] = (t + 256 < NBUCK) ? hist[t + 256] : 0;
    __syncthreads();
    for (int off = 1; off < 512; off <<= 1) {
        int a0 = (t >= off) ? sc[t - off] : 0;
        int a1 = sc[t + 256 - off];
        __syncthreads();
        sc[t] += a0; sc[t + 256] += a1;
        __syncthreads();
    }
    for (int i = t; i < NBUCK; i += 256) {
        int excl = sc[i] - hist[i];
        pref[i] = excl;
        cur[i] = excl;
    }
    if (t == 0) pref[NBUCK] = n;
    __syncthreads();
    for (int i = t; i < n; i += 256) {
        int s = ld_edge(ei, is64, e0 + i);
        int d = ld_edge(ei, is64, N_EDGES + e0 + i);
        int bk = d >> BSHIFT;
        int p = atomicAdd(&cur[bk], 1);
        stage[p] = ((unsigned int)(d & 511) << 18) | (unsigned int)s;
    }
    __syncthreads();
    for (int i = t; i < NBUCK; i += 256) {
        int c = hist[i];
        gb[i] = c ? atomicAdd(&bucketCursor[i], c) : 0;
    }
    __syncthreads();
    for (int p = t; p < n; p += 256) {
        int lo = 0, hi = NBUCK;
        while (hi - lo > 1) {
            int mid = (lo + hi) >> 1;
            if (pref[mid] <= p) lo = mid; else hi = mid;
        }
        bin[gb[lo] + (p - pref[lo])] = stage[p];
    }
}

// level-2: one block per bucket. Counting-sort the bucket's edges by key
// (q<<9)|local_dst (q = src/50000), emit per-(q,dst) u16 rowptr + dinv.
__global__ void __launch_bounds__(256)
k_bucketsort(const int* __restrict__ bucketBase, unsigned int* __restrict__ bin,
             float* __restrict__ dinv, unsigned short* __restrict__ seg16) {
    __shared__ int cnt[2048];
    __shared__ int cur[2048];
    __shared__ int tsum[256];
    __shared__ unsigned int payload[MAXBUCK];
    int b = blockIdx.x, t = threadIdx.x;
    int base = bucketBase[b], end = bucketBase[b + 1];
    int n = end - base;
    for (int i = t; i < 2048; i += 256) cnt[i] = 0;
    __syncthreads();
    // pass A: histogram over 2048 (q, local_dst) bins
    for (int i = t; i < n; i += 256) {
        unsigned int u = bin[base + i];
        int src = (int)(u & 0x3FFFFu);
        int key = ((src / 50000) << 9) | (int)(u >> 18);
        atomicAdd(&cnt[key], 1);
    }
    __syncthreads();
    // scan 2048: serial-8 per thread + Hillis-Steele over 256 thread sums
    int b0 = t * 8;
    int s = 0;
#pragma unroll
    for (int j = 0; j < 8; ++j) s += cnt[b0 + j];
    tsum[t] = s;
    __syncthreads();
    int v = s;
    for (int off = 1; off < 256; off <<= 1) {
        int add = (t >= off) ? tsum[t - off] : 0;
        __syncthreads();
        tsum[t] += add;
        __syncthreads();
    }
    int run = tsum[t] - v;  // exclusive prefix of this thread's chunk
#pragma unroll
    for (int j = 0; j < 8; ++j) { cur[b0 + j] = run; run += cnt[b0 + j]; }
    __syncthreads();
    // write u16 relative rowptr (before scatter mutates cur) + sentinel + dinv
    for (int i = t; i < 2048; i += 256)
        seg16[b * SEGSTRIDE + i] = (unsigned short)cur[i];
    if (t == 0) seg16[b * SEGSTRIDE + 2048] = (unsigned short)n;
    int node0 = b << BSHIFT;
    for (int d = t; d < 512; d += 256) {
        int node = node0 + d;
        if (node < N_NODES) {
            int deg = cnt[d] + cnt[512 + d] + cnt[1024 + d] + cnt[1536 + d];
            dinv[node] = rsqrtf((float)deg + 1.0f);
        }
    }
    __syncthreads();
    // pass B: scatter into payload by final position
    for (int i = t; i < n; i += 256) {
        unsigned int u = bin[base + i];
        int src = (int)(u & 0x3FFFFu);
        int key = ((src / 50000) << 9) | (int)(u >> 18);
        int p = atomicAdd(&cur[key], 1);
        if (p < MAXBUCK) payload[p] = u;
    }
    __syncthreads();
    // coalesced in-place write-back (sorted by (q, local_dst))
    for (int i = t; i < n; i += 256) bin[base + i] = payload[i];
}

// hs = dinv[i] * (x @ W), padded to stride 16 (one 64B line per row).
template <int FIN, int FOUT, int SIN>
__global__ void k_xw(const float* xin, const float* __restrict__ W,
                     const float* __restrict__ dinv, float* hs) {
    __shared__ float sW[FIN * FOUT];
    int t = threadIdx.x;
    if (t < FIN * FOUT) sW[t] = W[t];
    __syncthreads();
    int i = blockIdx.x * 256 + t;
    if (i >= N_NODES) return;
    float xi[FIN];
#pragma unroll
    for (int k = 0; k < FIN; ++k) xi[k] = xin[i * SIN + k];
    float di = dinv[i];
    float o[FOUT];
#pragma unroll
    for (int j = 0; j < FOUT; ++j) {
        float acc = 0.f;
#pragma unroll
        for (int k = 0; k < FIN; ++k) acc += xi[k] * sW[k * FOUT + j];
        o[j] = di * acc;
    }
#pragma unroll
    for (int j = 0; j < FOUT; ++j) hs[i * 16 + j] = o[j];
}

// Fused boundary kernel: x' = relu(dinv*(accG + hs_prev) + biasPrev);
// hs_next = dinv * (x' @ Wnext) -> B. Re-zeros accG for the next layer.
template <int FIN, int FOUT>
__global__ void k_fx(float* __restrict__ B, float* __restrict__ accG,
                     const float* __restrict__ dinv,
                     const float* __restrict__ biasPrev,
                     const float* __restrict__ Wnext) {
    __shared__ float sW[FIN * FOUT];
    __shared__ float sb[FIN];
    int t = threadIdx.x;
    if (t < FIN * FOUT) sW[t] = Wnext[t];
    if (t < FIN) sb[t] = biasPrev[t];
    __syncthreads();
    int i = blockIdx.x * 256 + t;
    if (i >= N_NODES) return;
    float di = dinv[i];
    float xi[FIN];
#pragma unroll
    for (int k = 0; k < FIN; ++k) {
        float v = di * (accG[i * 16 + k] + B[i * 16 + k]) + sb[k];
        xi[k] = fmaxf(v, 0.f);
    }
#pragma unroll
    for (int c = 0; c < 16; ++c) accG[i * 16 + c] = 0.f;
    float o[FOUT];
#pragma unroll
    for (int j = 0; j < FOUT; ++j) {
        float acc = 0.f;
#pragma unroll
        for (int k = 0; k < FIN; ++k) acc += xi[k] * sW[k * FOUT + j];
        o[j] = di * acc;
    }
#pragma unroll
    for (int j = 0; j < FOUT; ++j) B[i * 16 + j] = o[j];
}

// One block per (bucket, quarter, q). q = blk&3 -> XCD-pinned 3.2 MB src
// window. NEW vs R8: (a) the block's contiguous bin segment is staged into
// LDS once (coalesced; global fallback if > SEGMAX), removing bin from the
// VMEM dependency chain; (b) inner loop uses 8 named zero-init temporaries
// + unroll 2 => 16 independent hs loads expressed before any accumulate,
// forcing the scheduler to keep them in flight (VGPR target ~40-64).
// Flush: unsafeAtomicAdd, 16 consecutive lanes per dst = one 64B line RMW.
__global__ void __launch_bounds__(512)
k_agg(const int* __restrict__ bucketBase, const unsigned short* __restrict__ seg16,
      const unsigned int* __restrict__ bin, const float* __restrict__ hs,
      float* __restrict__ accG) {
    __shared__ unsigned short s_sr[132];
    __shared__ unsigned int s_bin[SEGMAX];
    int blk = blockIdx.x;
    int q = blk & 3;
    int Q = (blk >> 2) & 3;
    int b = blk >> 4;
    int t = threadIdx.x;
    int base = bucketBase[b];
    const unsigned short* sr = seg16 + b * SEGSTRIDE + (q << 9) + (Q << 7);
    if (t < 129) s_sr[t] = sr[t];
    __syncthreads();
    int s0 = (int)s_sr[0];
    int nseg = (int)s_sr[128] - s0;
    bool staged = (nseg <= SEGMAX);
    if (staged) {
        for (int i = t; i < nseg; i += 512) s_bin[i] = bin[base + s0 + i];
    }
    __syncthreads();
    int g = t >> 4, f = t & 15;
    int dd0 = g << 2;
    int r0 = (int)s_sr[dd0 + 0], r1 = (int)s_sr[dd0 + 1], r2 = (int)s_sr[dd0 + 2];
    int r3 = (int)s_sr[dd0 + 3], r4 = (int)s_sr[dd0 + 4];
    int n0 = r1 - r0, n1 = r2 - r1, n2 = r3 - r2, n3 = r4 - r3;
    float a0 = 0.f, a1 = 0.f, a2 = 0.f, a3 = 0.f;
    int m = max(max(n0, n1), max(n2, n3));
    if (staged) {
        int o0 = r0 - s0, o1 = r1 - s0, o2 = r2 - s0, o3 = r3 - s0;
#pragma unroll 2
        for (int k = 0; k < m; k += 2) {
            float t00 = 0.f, t01 = 0.f, t10 = 0.f, t11 = 0.f;
            float t20 = 0.f, t21 = 0.f, t30 = 0.f, t31 = 0.f;
            if (k     < n0) t00 = hs[((s_bin[o0 + k]     & 0x3FFFFu) << 4) + f];
            if (k + 1 < n0) t01 = hs[((s_bin[o0 + k + 1] & 0x3FFFFu) << 4) + f];
            if (k     < n1) t10 = hs[((s_bin[o1 + k]     & 0x3FFFFu) << 4) + f];
            if (k + 1 < n1) t11 = hs[((s_bin[o1 + k + 1] & 0x3FFFFu) << 4) + f];
            if (k     < n2) t20 = hs[((s_bin[o2 + k]     & 0x3FFFFu) << 4) + f];
            if (k + 1 < n2) t21 = hs[((s_bin[o2 + k + 1] & 0x3FFFFu) << 4) + f];
            if (k     < n3) t30 = hs[((s_bin[o3 + k]     & 0x3FFFFu) << 4) + f];
            if (k + 1 < n3) t31 = hs[((s_bin[o3 + k + 1] & 0x3FFFFu) << 4) + f];
            a0 += t00 + t01;
            a1 += t10 + t11;
            a2 += t20 + t21;
            a3 += t30 + t31;
        }
    } else {
        // fallback: direct global walk (R8 path) -- correctness safety net
        const unsigned int* p0 = bin + base + r0;
        const unsigned int* p1 = bin + base + r1;
        const unsigned int* p2 = bin + base + r2;
        const unsigned int* p3 = bin + base + r3;
#pragma unroll 2
        for (int k = 0; k < m; ++k) {
            if (k < n0) a0 += hs[((p0[k] & 0x3FFFFu) << 4) + f];
            if (k < n1) a1 += hs[((p1[k] & 0x3FFFFu) << 4) + f];
            if (k < n2) a2 += hs[((p2[k] & 0x3FFFFu) << 4) + f];
            if (k < n3) a3 += hs[((p3[k] & 0x3FFFFu) << 4) + f];
        }
    }
    int node0 = (b << BSHIFT) + (Q << 7) + dd0;
    if (node0 + 0 < N_NODES) unsafeAtomicAdd(&accG[((node0 + 0) << 4) + f], a0);
    if (node0 + 1 < N_NODES) unsafeAtomicAdd(&accG[((node0 + 1) << 4) + f], a1);
    if (node0 + 2 < N_NODES) unsafeAtomicAdd(&accG[((node0 + 2) << 4) + f], a2);
    if (node0 + 3 < N_NODES) unsafeAtomicAdd(&accG[((node0 + 3) << 4) + f], a3);
}

// out = dinv*(accG + hs_self) + bias, in place (accG aliases d_out).
template <int F, bool RELU>
__global__ void k_finish(float* __restrict__ B, float* __restrict__ accG,
                         const float* __restrict__ dinv,
                         const float* __restrict__ bias, float* __restrict__ out) {
    int i = blockIdx.x * blockDim.x + threadIdx.x;
    if (i >= N_NODES * 16) return;
    int node = i >> 4, ff = i & 15;
    float di = dinv[node];
    if (ff < F) {
        float r = di * (accG[i] + B[i]) + bias[ff];
        if (RELU) r = fmaxf(r, 0.f);
        out[node * 16 + ff] = r;
    }
}

extern "C" void kernel_launch(void* const* d_in, const int* in_sizes, int n_in,
                              void* d_out, int out_size, void* d_ws, size_t ws_size,
                              hipStream_t stream) {
    const float* x  = (const float*)d_in[0];
    const void*  ei = d_in[1];
    const float* W1 = (const float*)d_in[2];
    const float* b1 = (const float*)d_in[3];
    const float* W2 = (const float*)d_in[4];
    const float* b2 = (const float*)d_in[5];
    const float* W3 = (const float*)d_in[6];
    const float* b3 = (const float*)d_in[7];
    float* out = (float*)d_out;

    char* w = (char*)d_ws;
    int*   bucketCnt    = (int*)(w + 0);        //    2048 B (512 ints, zeroed)
    int*   bucketBase   = (int*)(w + 2048);     //    2048 B
    int*   bucketCursor = (int*)(w + 4096);     //    2048 B
    int*   flag         = (int*)(w + 6144);     //      64 B
    float* dinv         = (float*)(w + 6208);   //  800000 B
    unsigned short* seg16 = (unsigned short*)(w + 806208); // 391*2052*2 = 1604664 B
    unsigned int* bin   = (unsigned int*)(w + 2410880);    // 25600000 B
    float* B            = (float*)(w + 28010880);          // 12800000 B (N*16)
    float* accG         = out;                  // d_out doubles as accumulator
    // total ws use ~40.8 MB

    // ---- zero accumulator + build (q,dst)-sorted bucketed edges ----
    k_zero<<<12500, 256, 0, stream>>>((int*)accG, N_NODES * 16);
    k_zero<<<2, 256, 0, stream>>>(bucketCnt, 512);
    k_detect<<<1, 256, 0, stream>>>((const unsigned int*)ei, flag);
    k_hist<<<1024, 256, 0, stream>>>(ei, flag, bucketCnt);
    k_scan_buckets<<<1, 256, 0, stream>>>(bucketCnt, bucketBase, bucketCursor);
    k_binscatter<<<NCHUNK, 256, 0, stream>>>(ei, flag, bucketCursor, bin);
    k_bucketsort<<<NBUCK, 256, 0, stream>>>(bucketBase, bin, dinv, seg16);

    // ---- layer 1 ----
    k_xw<11, 11, 11><<<782, 256, 0, stream>>>(x, W1, dinv, B);
    k_agg<<<NBUCK * 16, 512, 0, stream>>>(bucketBase, seg16, bin, B, accG);
    // ---- boundary 1: finish L1 + xw L2 (re-zeros accG) ----
    k_fx<11, 11><<<782, 256, 0, stream>>>(B, accG, dinv, b1, W2);
    // ---- layer 2 ----
    k_agg<<<NBUCK * 16, 512, 0, stream>>>(bucketBase, seg16, bin, B, accG);
    // ---- boundary 2: finish L2 + xw L3 (re-zeros accG) ----
    k_fx<11, 16><<<782, 256, 0, stream>>>(B, accG, dinv, b2, W3);
    // ---- layer 3 ----
    k_agg<<<NBUCK * 16, 512, 0, stream>>>(bucketBase, seg16, bin, B, accG);
    k_finish<16, false><<<12500, 256, 0, stream>>>(B, accG, dinv, b3, out);
}

// Round 10
// 322.407 us; speedup vs baseline: 2.6407x; 1.3236x over previous
//
#include <hip/hip_runtime.h>

#define N_NODES 200000
#define N_EDGES 6400000

constexpr int BSHIFT = 9;                      // 512 nodes per bucket
constexpr int NBUCK  = (N_NODES + 511) / 512;  // 391
constexpr int CHUNK  = 16384;
constexpr int NCHUNK = (N_EDGES + CHUNK - 1) / CHUNK;  // 391
constexpr int MAXBUCK = 18432;                 // lambda=16384, +16 sigma
constexpr int SEGSTRIDE = 2052;                // 2048 bins + end sentinel + pad
constexpr int SEGMAX = 1536;                   // staged edges per (b,Q,q); lambda=1024

// ---- edge index load helper: handles int32 or int64 storage ----
__device__ __forceinline__ int ld_edge(const void* ei, int is64, int idx) {
    return is64 ? (int)((const long long*)ei)[idx] : ((const int*)ei)[idx];
}

__global__ void k_zero(int* __restrict__ p, int n) {
    int i = blockIdx.x * blockDim.x + threadIdx.x;
    if (i < n) p[i] = 0;
}

// int64 little-endian values < 2^31  =>  every odd u32 slot is 0
__global__ void k_detect(const unsigned int* __restrict__ ei, int* __restrict__ flag) {
    __shared__ int nz;
    if (threadIdx.x == 0) nz = 0;
    __syncthreads();
    if (ei[2 * threadIdx.x + 1] != 0u) atomicOr(&nz, 1);
    __syncthreads();
    if (threadIdx.x == 0) *flag = nz ? 0 : 1;
}

// bucket histogram: LDS-accumulated, one global atomic per bucket per block
__global__ void k_hist(const void* __restrict__ ei, const int* __restrict__ flag,
                       int* __restrict__ bucketCnt) {
    __shared__ int h[NBUCK];
    for (int i = threadIdx.x; i < NBUCK; i += 256) h[i] = 0;
    __syncthreads();
    const int is64 = *flag;
    int stride = gridDim.x * blockDim.x;
    for (int e = blockIdx.x * 256 + threadIdx.x; e < N_EDGES; e += stride) {
        int d = ld_edge(ei, is64, N_EDGES + e);
        atomicAdd(&h[d >> BSHIFT], 1);
    }
    __syncthreads();
    for (int i = threadIdx.x; i < NBUCK; i += 256)
        if (h[i]) atomicAdd(&bucketCnt[i], h[i]);
}

// single-block scan of 391 bucket counts -> exclusive bases + cursors
__global__ void k_scan_buckets(const int* __restrict__ bucketCnt,
                               int* __restrict__ bucketBase,
                               int* __restrict__ bucketCursor) {
    __shared__ int sc[512];
    int t = threadIdx.x;
    sc[t]       = (t < NBUCK)       ? bucketCnt[t]       : 0;
    sc[t + 256] = (t + 256 < NBUCK) ? bucketCnt[t + 256] : 0;
    __syncthreads();
    for (int off = 1; off < 512; off <<= 1) {
        int a0 = (t >= off) ? sc[t - off] : 0;
        int a1 = sc[t + 256 - off];
        __syncthreads();
        sc[t] += a0; sc[t + 256] += a1;
        __syncthreads();
    }
    for (int i = t; i < NBUCK; i += 256) {
        int excl = sc[i] - bucketCnt[i];
        bucketBase[i] = excl;
        bucketCursor[i] = excl;
    }
    if (t == 0) bucketBase[NBUCK] = N_EDGES;
}

// level-1: bin a 16K-edge chunk by bucket in LDS, write contiguous runs.
// 1024 threads (32 waves/CU at 2 blocks resident). Write-out: one wave per
// bucket run (no binary search).
__global__ void __launch_bounds__(1024)
k_binscatter(const void* __restrict__ ei, const int* __restrict__ flag,
             int* __restrict__ bucketCursor, unsigned int* __restrict__ bin) {
    __shared__ int hist[NBUCK];
    __shared__ int pref[NBUCK + 1];
    __shared__ int cur[NBUCK];
    __shared__ int gb[NBUCK];
    __shared__ int sc[512];
    __shared__ unsigned int stage[CHUNK];
    const int is64 = *flag;
    int b = blockIdx.x, t = threadIdx.x;
    int e0 = b * CHUNK;
    int n = min(CHUNK, N_EDGES - e0);
    for (int i = t; i < NBUCK; i += 1024) hist[i] = 0;
    __syncthreads();
    // pass A: per-chunk bucket histogram
    for (int i = t; i < n; i += 1024) {
        int d = ld_edge(ei, is64, N_EDGES + e0 + i);
        atomicAdd(&hist[d >> BSHIFT], 1);
    }
    __syncthreads();
    // scan 512 entries (threads 0-255 work, all barrier)
    if (t < 256) {
        sc[t]       = (t < NBUCK)       ? hist[t]       : 0;
        sc[t + 256] = (t + 256 < NBUCK) ? hist[t + 256] : 0;
    }
    __syncthreads();
    for (int off = 1; off < 512; off <<= 1) {
        int a0 = 0, a1 = 0;
        if (t < 256) {
            a0 = (t >= off) ? sc[t - off] : 0;
            a1 = sc[t + 256 - off];
        }
        __syncthreads();
        if (t < 256) { sc[t] += a0; sc[t + 256] += a1; }
        __syncthreads();
    }
    for (int i = t; i < NBUCK; i += 1024) {
        int excl = sc[i] - hist[i];
        pref[i] = excl;
        cur[i] = excl;
    }
    if (t == 0) pref[NBUCK] = n;
    __syncthreads();
    // pass B: scatter packed (local_d<<18 | src) into LDS stage, bucket-grouped
    for (int i = t; i < n; i += 1024) {
        int s = ld_edge(ei, is64, e0 + i);
        int d = ld_edge(ei, is64, N_EDGES + e0 + i);
        int bk = d >> BSHIFT;
        int p = atomicAdd(&cur[bk], 1);
        stage[p] = ((unsigned int)(d & 511) << 18) | (unsigned int)s;
    }
    __syncthreads();
    // reserve global ranges, one atomic per non-empty bucket
    for (int i = t; i < NBUCK; i += 1024) {
        int c = hist[i];
        gb[i] = c ? atomicAdd(&bucketCursor[i], c) : 0;
    }
    __syncthreads();
    // write-out: wave w copies buckets w, w+16, ... (contiguous runs)
    int wave = t >> 6, lane = t & 63;
    for (int i = wave; i < NBUCK; i += 16) {
        int c = hist[i];
        if (!c) continue;
        int pp = pref[i], gg = gb[i];
        for (int j = lane; j < c; j += 64) bin[gg + j] = stage[pp + j];
    }
}

// level-2: one block per bucket, 1024 threads. Counting-sort the bucket's
// edges by key (q<<9)|local_dst (q = src/50000), emit u16 rowptr + dinv.
__global__ void __launch_bounds__(1024)
k_bucketsort(const int* __restrict__ bucketBase, unsigned int* __restrict__ bin,
             float* __restrict__ dinv, unsigned short* __restrict__ seg16) {
    __shared__ int cnt[2048];
    __shared__ int cur[2048];
    __shared__ int tsum[1024];
    __shared__ unsigned int payload[MAXBUCK];
    int b = blockIdx.x, t = threadIdx.x;
    int base = bucketBase[b], end = bucketBase[b + 1];
    int n = end - base;
    cnt[t] = 0; cnt[t + 1024] = 0;
    __syncthreads();
    // pass A: histogram over 2048 (q, local_dst) bins
    for (int i = t; i < n; i += 1024) {
        unsigned int u = bin[base + i];
        int src = (int)(u & 0x3FFFFu);
        int key = ((src / 50000) << 9) | (int)(u >> 18);
        atomicAdd(&cnt[key], 1);
    }
    __syncthreads();
    // scan 2048: serial-2 per thread + Hillis-Steele over 1024 thread sums
    int b0 = t * 2;
    int s = cnt[b0] + cnt[b0 + 1];
    tsum[t] = s;
    __syncthreads();
    int v = s;
    for (int off = 1; off < 1024; off <<= 1) {
        int add = (t >= off) ? tsum[t - off] : 0;
        __syncthreads();
        tsum[t] += add;
        __syncthreads();
    }
    int run = tsum[t] - v;  // exclusive prefix of this thread's pair
    cur[b0] = run;
    cur[b0 + 1] = run + cnt[b0];
    __syncthreads();
    // write u16 relative rowptr (before scatter mutates cur) + sentinel + dinv
    for (int i = t; i < 2048; i += 1024)
        seg16[b * SEGSTRIDE + i] = (unsigned short)cur[i];
    if (t == 0) seg16[b * SEGSTRIDE + 2048] = (unsigned short)n;
    int node0 = b << BSHIFT;
    if (t < 512) {
        int node = node0 + t;
        if (node < N_NODES) {
            int deg = cnt[t] + cnt[512 + t] + cnt[1024 + t] + cnt[1536 + t];
            dinv[node] = rsqrtf((float)deg + 1.0f);
        }
    }
    __syncthreads();
    // pass B: scatter into payload by final position
    for (int i = t; i < n; i += 1024) {
        unsigned int u = bin[base + i];
        int src = (int)(u & 0x3FFFFu);
        int key = ((src / 50000) << 9) | (int)(u >> 18);
        int p = atomicAdd(&cur[key], 1);
        if (p < MAXBUCK) payload[p] = u;
    }
    __syncthreads();
    // coalesced in-place write-back (sorted by (q, local_dst))
    for (int i = t; i < n; i += 1024) bin[base + i] = payload[i];
}

// hs = dinv[i] * (x @ W), padded to stride 16 (one 64B line per row).
template <int FIN, int FOUT, int SIN>
__global__ void k_xw(const float* xin, const float* __restrict__ W,
                     const float* __restrict__ dinv, float* hs) {
    __shared__ float sW[FIN * FOUT];
    int t = threadIdx.x;
    if (t < FIN * FOUT) sW[t] = W[t];
    __syncthreads();
    int i = blockIdx.x * 256 + t;
    if (i >= N_NODES) return;
    float xi[FIN];
#pragma unroll
    for (int k = 0; k < FIN; ++k) xi[k] = xin[i * SIN + k];
    float di = dinv[i];
    float o[FOUT];
#pragma unroll
    for (int j = 0; j < FOUT; ++j) {
        float acc = 0.f;
#pragma unroll
        for (int k = 0; k < FIN; ++k) acc += xi[k] * sW[k * FOUT + j];
        o[j] = di * acc;
    }
#pragma unroll
    for (int j = 0; j < FOUT; ++j) hs[i * 16 + j] = o[j];
}

// Fused boundary kernel: x' = relu(dinv*(accG + hs_prev) + biasPrev);
// hs_next = dinv * (x' @ Wnext) -> B. Re-zeros accG for the next layer.
template <int FIN, int FOUT>
__global__ void k_fx(float* __restrict__ B, float* __restrict__ accG,
                     const float* __restrict__ dinv,
                     const float* __restrict__ biasPrev,
                     const float* __restrict__ Wnext) {
    __shared__ float sW[FIN * FOUT];
    __shared__ float sb[FIN];
    int t = threadIdx.x;
    if (t < FIN * FOUT) sW[t] = Wnext[t];
    if (t < FIN) sb[t] = biasPrev[t];
    __syncthreads();
    int i = blockIdx.x * 256 + t;
    if (i >= N_NODES) return;
    float di = dinv[i];
    float xi[FIN];
#pragma unroll
    for (int k = 0; k < FIN; ++k) {
        float v = di * (accG[i * 16 + k] + B[i * 16 + k]) + sb[k];
        xi[k] = fmaxf(v, 0.f);
    }
#pragma unroll
    for (int c = 0; c < 16; ++c) accG[i * 16 + c] = 0.f;
    float o[FOUT];
#pragma unroll
    for (int j = 0; j < FOUT; ++j) {
        float acc = 0.f;
#pragma unroll
        for (int k = 0; k < FIN; ++k) acc += xi[k] * sW[k * FOUT + j];
        o[j] = di * acc;
    }
#pragma unroll
    for (int j = 0; j < FOUT; ++j) B[i * 16 + j] = o[j];
}

// One block per (bucket, quarter, q). q = blk&3 -> XCD-pinned 3.2 MB src
// window; bin segment staged to LDS (coalesced) so the only VMEM chain is
// the hs gather; 8 named zero-init temporaries + unroll 2 keep ~16
// independent hs loads in flight. Flush: unsafeAtomicAdd, 16 consecutive
// lanes per dst = one 64B line RMW.
__global__ void __launch_bounds__(512)
k_agg(const int* __restrict__ bucketBase, const unsigned short* __restrict__ seg16,
      const unsigned int* __restrict__ bin, const float* __restrict__ hs,
      float* __restrict__ accG) {
    __shared__ unsigned short s_sr[132];
    __shared__ unsigned int s_bin[SEGMAX];
    int blk = blockIdx.x;
    int q = blk & 3;
    int Q = (blk >> 2) & 3;
    int b = blk >> 4;
    int t = threadIdx.x;
    int base = bucketBase[b];
    const unsigned short* sr = seg16 + b * SEGSTRIDE + (q << 9) + (Q << 7);
    if (t < 129) s_sr[t] = sr[t];
    __syncthreads();
    int s0 = (int)s_sr[0];
    int nseg = (int)s_sr[128] - s0;
    bool staged = (nseg <= SEGMAX);
    if (staged) {
        for (int i = t; i < nseg; i += 512) s_bin[i] = bin[base + s0 + i];
    }
    __syncthreads();
    int g = t >> 4, f = t & 15;
    int dd0 = g << 2;
    int r0 = (int)s_sr[dd0 + 0], r1 = (int)s_sr[dd0 + 1], r2 = (int)s_sr[dd0 + 2];
    int r3 = (int)s_sr[dd0 + 3], r4 = (int)s_sr[dd0 + 4];
    int n0 = r1 - r0, n1 = r2 - r1, n2 = r3 - r2, n3 = r4 - r3;
    float a0 = 0.f, a1 = 0.f, a2 = 0.f, a3 = 0.f;
    int m = max(max(n0, n1), max(n2, n3));
    if (staged) {
        int o0 = r0 - s0, o1 = r1 - s0, o2 = r2 - s0, o3 = r3 - s0;
#pragma unroll 2
        for (int k = 0; k < m; k += 2) {
            float t00 = 0.f, t01 = 0.f, t10 = 0.f, t11 = 0.f;
            float t20 = 0.f, t21 = 0.f, t30 = 0.f, t31 = 0.f;
            if (k     < n0) t00 = hs[((s_bin[o0 + k]     & 0x3FFFFu) << 4) + f];
            if (k + 1 < n0) t01 = hs[((s_bin[o0 + k + 1] & 0x3FFFFu) << 4) + f];
            if (k     < n1) t10 = hs[((s_bin[o1 + k]     & 0x3FFFFu) << 4) + f];
            if (k + 1 < n1) t11 = hs[((s_bin[o1 + k + 1] & 0x3FFFFu) << 4) + f];
            if (k     < n2) t20 = hs[((s_bin[o2 + k]     & 0x3FFFFu) << 4) + f];
            if (k + 1 < n2) t21 = hs[((s_bin[o2 + k + 1] & 0x3FFFFu) << 4) + f];
            if (k     < n3) t30 = hs[((s_bin[o3 + k]     & 0x3FFFFu) << 4) + f];
            if (k + 1 < n3) t31 = hs[((s_bin[o3 + k + 1] & 0x3FFFFu) << 4) + f];
            a0 += t00 + t01;
            a1 += t10 + t11;
            a2 += t20 + t21;
            a3 += t30 + t31;
        }
    } else {
        // fallback: direct global walk -- correctness safety net
        const unsigned int* p0 = bin + base + r0;
        const unsigned int* p1 = bin + base + r1;
        const unsigned int* p2 = bin + base + r2;
        const unsigned int* p3 = bin + base + r3;
#pragma unroll 2
        for (int k = 0; k < m; ++k) {
            if (k < n0) a0 += hs[((p0[k] & 0x3FFFFu) << 4) + f];
            if (k < n1) a1 += hs[((p1[k] & 0x3FFFFu) << 4) + f];
            if (k < n2) a2 += hs[((p2[k] & 0x3FFFFu) << 4) + f];
            if (k < n3) a3 += hs[((p3[k] & 0x3FFFFu) << 4) + f];
        }
    }
    int node0 = (b << BSHIFT) + (Q << 7) + dd0;
    if (node0 + 0 < N_NODES) unsafeAtomicAdd(&accG[((node0 + 0) << 4) + f], a0);
    if (node0 + 1 < N_NODES) unsafeAtomicAdd(&accG[((node0 + 1) << 4) + f], a1);
    if (node0 + 2 < N_NODES) unsafeAtomicAdd(&accG[((node0 + 2) << 4) + f], a2);
    if (node0 + 3 < N_NODES) unsafeAtomicAdd(&accG[((node0 + 3) << 4) + f], a3);
}

// out = dinv*(accG + hs_self) + bias, in place (accG aliases d_out).
template <int F, bool RELU>
__global__ void k_finish(float* __restrict__ B, float* __restrict__ accG,
                         const float* __restrict__ dinv,
                         const float* __restrict__ bias, float* __restrict__ out) {
    int i = blockIdx.x * blockDim.x + threadIdx.x;
    if (i >= N_NODES * 16) return;
    int node = i >> 4, ff = i & 15;
    float di = dinv[node];
    if (ff < F) {
        float r = di * (accG[i] + B[i]) + bias[ff];
        if (RELU) r = fmaxf(r, 0.f);
        out[node * 16 + ff] = r;
    }
}

extern "C" void kernel_launch(void* const* d_in, const int* in_sizes, int n_in,
                              void* d_out, int out_size, void* d_ws, size_t ws_size,
                              hipStream_t stream) {
    const float* x  = (const float*)d_in[0];
    const void*  ei = d_in[1];
    const float* W1 = (const float*)d_in[2];
    const float* b1 = (const float*)d_in[3];
    const float* W2 = (const float*)d_in[4];
    const float* b2 = (const float*)d_in[5];
    const float* W3 = (const float*)d_in[6];
    const float* b3 = (const float*)d_in[7];
    float* out = (float*)d_out;

    char* w = (char*)d_ws;
    int*   bucketCnt    = (int*)(w + 0);        //    2048 B (512 ints, zeroed)
    int*   bucketBase   = (int*)(w + 2048);     //    2048 B
    int*   bucketCursor = (int*)(w + 4096);     //    2048 B
    int*   flag         = (int*)(w + 6144);     //      64 B
    float* dinv         = (float*)(w + 6208);   //  800000 B
    unsigned short* seg16 = (unsigned short*)(w + 806208); // 391*2052*2 = 1604664 B
    unsigned int* bin   = (unsigned int*)(w + 2410880);    // 25600000 B
    float* B            = (float*)(w + 28010880);          // 12800000 B (N*16)
    float* accG         = out;                  // d_out doubles as accumulator
    // total ws use ~40.8 MB

    // ---- zero accumulator + build (q,dst)-sorted bucketed edges ----
    k_zero<<<12500, 256, 0, stream>>>((int*)accG, N_NODES * 16);
    k_zero<<<2, 256, 0, stream>>>(bucketCnt, 512);
    k_detect<<<1, 256, 0, stream>>>((const unsigned int*)ei, flag);
    k_hist<<<1024, 256, 0, stream>>>(ei, flag, bucketCnt);
    k_scan_buckets<<<1, 256, 0, stream>>>(bucketCnt, bucketBase, bucketCursor);
    k_binscatter<<<NCHUNK, 1024, 0, stream>>>(ei, flag, bucketCursor, bin);
    k_bucketsort<<<NBUCK, 1024, 0, stream>>>(bucketBase, bin, dinv, seg16);

    // ---- layer 1 ----
    k_xw<11, 11, 11><<<782, 256, 0, stream>>>(x, W1, dinv, B);
    k_agg<<<NBUCK * 16, 512, 0, stream>>>(bucketBase, seg16, bin, B, accG);
    // ---- boundary 1: finish L1 + xw L2 (re-zeros accG) ----
    k_fx<11, 11><<<782, 256, 0, stream>>>(B, accG, dinv, b1, W2);
    // ---- layer 2 ----
    k_agg<<<NBUCK * 16, 512, 0, stream>>>(bucketBase, seg16, bin, B, accG);
    // ---- boundary 2: finish L2 + xw L3 (re-zeros accG) ----
    k_fx<11, 16><<<782, 256, 0, stream>>>(B, accG, dinv, b2, W3);
    // ---- layer 3 ----
    k_agg<<<NBUCK * 16, 512, 0, stream>>>(bucketBase, seg16, bin, B, accG);
    k_finish<16, false><<<12500, 256, 0, stream>>>(B, accG, dinv, b3, out);
}

// Round 11
// 293.552 us; speedup vs baseline: 2.9003x; 1.0983x over previous
//
#include <hip/hip_runtime.h>

#define N_NODES 200000
#define N_EDGES 6400000

constexpr int BSHIFT = 9;                      // 512 nodes per bucket
constexpr int NBUCK  = (N_NODES + 511) / 512;  // 391
constexpr int CHUNK  = 16384;
constexpr int NCHUNK = (N_EDGES + CHUNK - 1) / CHUNK;  // 391
constexpr int MAXBUCK = 18432;                 // fixed slot per bucket; lambda=16368, +16 sigma
constexpr int SEGSTRIDE = 2052;                // 2048 bins + end sentinel + pad
constexpr int SEGMAX = 1536;                   // staged edges per (b,Q,q); lambda=1024

// ---- edge index load helper: handles int32 or int64 storage ----
__device__ __forceinline__ int ld_edge(const void* ei, int is64, int idx) {
    return is64 ? (int)((const long long*)ei)[idx] : ((const int*)ei)[idx];
}

__global__ void k_zero(int* __restrict__ p, int n) {
    int i = blockIdx.x * blockDim.x + threadIdx.x;
    if (i < n) p[i] = 0;
}

// cursor[i] = i * MAXBUCK (fixed-stride bucket bases)
__global__ void k_iota(int* __restrict__ cursor) {
    int i = threadIdx.x;
    if (i < NBUCK) cursor[i] = i * MAXBUCK;
}

// int64 little-endian values < 2^31  =>  every odd u32 slot is 0
__global__ void k_detect(const unsigned int* __restrict__ ei, int* __restrict__ flag) {
    __shared__ int nz;
    if (threadIdx.x == 0) nz = 0;
    __syncthreads();
    if (ei[2 * threadIdx.x + 1] != 0u) atomicOr(&nz, 1);
    __syncthreads();
    if (threadIdx.x == 0) *flag = nz ? 0 : 1;
}

// level-1: bin a 16K-edge chunk by dst-bucket in LDS, write contiguous runs
// into the bucket's FIXED slot (no global histogram needed). Staged word
// packs (q<<27)|(local_dst<<18)|src so bucketsort never divides.
__global__ void __launch_bounds__(1024)
k_binscatter(const void* __restrict__ ei, const int* __restrict__ flag,
             int* __restrict__ bucketCursor, unsigned int* __restrict__ bin) {
    __shared__ int hist[NBUCK];
    __shared__ int pref[NBUCK + 1];
    __shared__ int cur[NBUCK];
    __shared__ int gb[NBUCK];
    __shared__ int sc[512];
    __shared__ unsigned int stage[CHUNK];
    const int is64 = *flag;
    int b = blockIdx.x, t = threadIdx.x;
    int e0 = b * CHUNK;
    int n = min(CHUNK, N_EDGES - e0);
    for (int i = t; i < NBUCK; i += 1024) hist[i] = 0;
    __syncthreads();
    // pass A: per-chunk bucket histogram
    for (int i = t; i < n; i += 1024) {
        int d = ld_edge(ei, is64, N_EDGES + e0 + i);
        atomicAdd(&hist[d >> BSHIFT], 1);
    }
    __syncthreads();
    // scan 512 entries (threads 0-255 work, all barrier)
    if (t < 256) {
        sc[t]       = (t < NBUCK)       ? hist[t]       : 0;
        sc[t + 256] = (t + 256 < NBUCK) ? hist[t + 256] : 0;
    }
    __syncthreads();
    for (int off = 1; off < 512; off <<= 1) {
        int a0 = 0, a1 = 0;
        if (t < 256) {
            a0 = (t >= off) ? sc[t - off] : 0;
            a1 = sc[t + 256 - off];
        }
        __syncthreads();
        if (t < 256) { sc[t] += a0; sc[t + 256] += a1; }
        __syncthreads();
    }
    for (int i = t; i < NBUCK; i += 1024) {
        int excl = sc[i] - hist[i];
        pref[i] = excl;
        cur[i] = excl;
    }
    if (t == 0) pref[NBUCK] = n;
    __syncthreads();
    // pass B: scatter packed (q<<27)|(local_d<<18)|src into LDS stage
    for (int i = t; i < n; i += 1024) {
        int s = ld_edge(ei, is64, e0 + i);
        int d = ld_edge(ei, is64, N_EDGES + e0 + i);
        int bk = d >> BSHIFT;
        unsigned int q = (unsigned int)s / 50000u;
        int p = atomicAdd(&cur[bk], 1);
        stage[p] = (q << 27) | ((unsigned int)(d & 511) << 18) | (unsigned int)s;
    }
    __syncthreads();
    // reserve global ranges in fixed slots, one atomic per non-empty bucket
    for (int i = t; i < NBUCK; i += 1024) {
        int c = hist[i];
        gb[i] = c ? atomicAdd(&bucketCursor[i], c) : 0;
    }
    __syncthreads();
    // write-out: wave w copies buckets w, w+16, ... (contiguous runs);
    // clamp to slot end (16-sigma safety, never expected to trigger)
    int wave = t >> 6, lane = t & 63;
    for (int i = wave; i < NBUCK; i += 16) {
        int c = hist[i];
        if (!c) continue;
        int gg = gb[i];
        int room = (i + 1) * MAXBUCK - gg;
        int lim = min(c, max(room, 0));
        int pp = pref[i];
        for (int j = lane; j < lim; j += 64) bin[gg + j] = stage[pp + j];
    }
}

// level-2: one block per bucket, 1024 threads. Counting-sort the bucket's
// edges by key (q<<9)|local_dst, emit u16 rowptr + dinv. Payload written
// back as src<<4 (pre-shifted hs row offset) -- k_agg does ONE v_add.
__global__ void __launch_bounds__(1024)
k_bucketsort(const int* __restrict__ bucketCursor, unsigned int* __restrict__ bin,
             float* __restrict__ dinv, unsigned short* __restrict__ seg16) {
    __shared__ int cnt[2048];
    __shared__ int cur[2048];
    __shared__ int tsum[1024];
    __shared__ unsigned int payload[MAXBUCK];
    int b = blockIdx.x, t = threadIdx.x;
    int base = b * MAXBUCK;
    int n = min(bucketCursor[b] - base, MAXBUCK);
    cnt[t] = 0; cnt[t + 1024] = 0;
    __syncthreads();
    // pass A: histogram over 2048 (q, local_dst) bins
    for (int i = t; i < n; i += 1024) {
        unsigned int u = bin[base + i];
        int key = (int)((u >> 27) << 9) | (int)((u >> 18) & 511u);
        atomicAdd(&cnt[key], 1);
    }
    __syncthreads();
    // scan 2048: serial-2 per thread + Hillis-Steele over 1024 thread sums
    int b0 = t * 2;
    int s = cnt[b0] + cnt[b0 + 1];
    tsum[t] = s;
    __syncthreads();
    int v = s;
    for (int off = 1; off < 1024; off <<= 1) {
        int add = (t >= off) ? tsum[t - off] : 0;
        __syncthreads();
        tsum[t] += add;
        __syncthreads();
    }
    int run = tsum[t] - v;  // exclusive prefix of this thread's pair
    cur[b0] = run;
    cur[b0 + 1] = run + cnt[b0];
    __syncthreads();
    // write u16 relative rowptr (before scatter mutates cur) + sentinel + dinv
    for (int i = t; i < 2048; i += 1024)
        seg16[b * SEGSTRIDE + i] = (unsigned short)cur[i];
    if (t == 0) seg16[b * SEGSTRIDE + 2048] = (unsigned short)n;
    int node0 = b << BSHIFT;
    if (t < 512) {
        int node = node0 + t;
        if (node < N_NODES) {
            int deg = cnt[t] + cnt[512 + t] + cnt[1024 + t] + cnt[1536 + t];
            dinv[node] = rsqrtf((float)deg + 1.0f);
        }
    }
    __syncthreads();
    // pass B: scatter src<<4 into payload by final position
    for (int i = t; i < n; i += 1024) {
        unsigned int u = bin[base + i];
        int key = (int)((u >> 27) << 9) | (int)((u >> 18) & 511u);
        int p = atomicAdd(&cur[key], 1);
        if (p < MAXBUCK) payload[p] = (u & 0x3FFFFu) << 4;
    }
    __syncthreads();
    // coalesced in-place write-back (sorted by (q, local_dst))
    for (int i = t; i < n; i += 1024) bin[base + i] = payload[i];
}

// hs = dinv[i] * (x @ W), padded to stride 16 (one 64B line per row).
template <int FIN, int FOUT, int SIN>
__global__ void k_xw(const float* xin, const float* __restrict__ W,
                     const float* __restrict__ dinv, float* hs) {
    __shared__ float sW[FIN * FOUT];
    int t = threadIdx.x;
    if (t < FIN * FOUT) sW[t] = W[t];
    __syncthreads();
    int i = blockIdx.x * 256 + t;
    if (i >= N_NODES) return;
    float xi[FIN];
#pragma unroll
    for (int k = 0; k < FIN; ++k) xi[k] = xin[i * SIN + k];
    float di = dinv[i];
    float o[FOUT];
#pragma unroll
    for (int j = 0; j < FOUT; ++j) {
        float acc = 0.f;
#pragma unroll
        for (int k = 0; k < FIN; ++k) acc += xi[k] * sW[k * FOUT + j];
        o[j] = di * acc;
    }
#pragma unroll
    for (int j = 0; j < FOUT; ++j) hs[i * 16 + j] = o[j];
}

// Fused boundary kernel: x' = relu(dinv*(accG + hs_prev) + biasPrev);
// hs_next = dinv * (x' @ Wnext) -> B. Re-zeros accG for the next layer.
template <int FIN, int FOUT>
__global__ void k_fx(float* __restrict__ B, float* __restrict__ accG,
                     const float* __restrict__ dinv,
                     const float* __restrict__ biasPrev,
                     const float* __restrict__ Wnext) {
    __shared__ float sW[FIN * FOUT];
    __shared__ float sb[FIN];
    int t = threadIdx.x;
    if (t < FIN * FOUT) sW[t] = Wnext[t];
    if (t < FIN) sb[t] = biasPrev[t];
    __syncthreads();
    int i = blockIdx.x * 256 + t;
    if (i >= N_NODES) return;
    float di = dinv[i];
    float xi[FIN];
#pragma unroll
    for (int k = 0; k < FIN; ++k) {
        float v = di * (accG[i * 16 + k] + B[i * 16 + k]) + sb[k];
        xi[k] = fmaxf(v, 0.f);
    }
#pragma unroll
    for (int c = 0; c < 16; ++c) accG[i * 16 + c] = 0.f;
    float o[FOUT];
#pragma unroll
    for (int j = 0; j < FOUT; ++j) {
        float acc = 0.f;
#pragma unroll
        for (int k = 0; k < FIN; ++k) acc += xi[k] * sW[k * FOUT + j];
        o[j] = di * acc;
    }
#pragma unroll
    for (int j = 0; j < FOUT; ++j) B[i * 16 + j] = o[j];
}

// One block per (bucket, quarter, q). q = blk&3 -> XCD-pinned 3.2 MB src
// window; bin segment staged to LDS; payload is pre-shifted src<<4 so each
// gather is hs[s_bin[o+k] + f] (one v_add). 8 named zero-init temporaries
// + unroll 2 keep ~16 independent hs loads in flight. Flush:
// unsafeAtomicAdd, 16 consecutive lanes per dst = one 64B line RMW.
__global__ void __launch_bounds__(512)
k_agg(const unsigned short* __restrict__ seg16,
      const unsigned int* __restrict__ bin, const float* __restrict__ hs,
      float* __restrict__ accG) {
    __shared__ unsigned short s_sr[132];
    __shared__ unsigned int s_bin[SEGMAX];
    int blk = blockIdx.x;
    int q = blk & 3;
    int Q = (blk >> 2) & 3;
    int b = blk >> 4;
    int t = threadIdx.x;
    int base = b * MAXBUCK;
    const unsigned short* sr = seg16 + b * SEGSTRIDE + (q << 9) + (Q << 7);
    if (t < 129) s_sr[t] = sr[t];
    __syncthreads();
    int s0 = (int)s_sr[0];
    int nseg = (int)s_sr[128] - s0;
    bool staged = (nseg <= SEGMAX);
    if (staged) {
        for (int i = t; i < nseg; i += 512) s_bin[i] = bin[base + s0 + i];
    }
    __syncthreads();
    int g = t >> 4, f = t & 15;
    int dd0 = g << 2;
    int r0 = (int)s_sr[dd0 + 0], r1 = (int)s_sr[dd0 + 1], r2 = (int)s_sr[dd0 + 2];
    int r3 = (int)s_sr[dd0 + 3], r4 = (int)s_sr[dd0 + 4];
    int n0 = r1 - r0, n1 = r2 - r1, n2 = r3 - r2, n3 = r4 - r3;
    float a0 = 0.f, a1 = 0.f, a2 = 0.f, a3 = 0.f;
    int m = max(max(n0, n1), max(n2, n3));
    if (staged) {
        int o0 = r0 - s0, o1 = r1 - s0, o2 = r2 - s0, o3 = r3 - s0;
#pragma unroll 2
        for (int k = 0; k < m; k += 2) {
            float t00 = 0.f, t01 = 0.f, t10 = 0.f, t11 = 0.f;
            float t20 = 0.f, t21 = 0.f, t30 = 0.f, t31 = 0.f;
            if (k     < n0) t00 = hs[s_bin[o0 + k]     + f];
            if (k + 1 < n0) t01 = hs[s_bin[o0 + k + 1] + f];
            if (k     < n1) t10 = hs[s_bin[o1 + k]     + f];
            if (k + 1 < n1) t11 = hs[s_bin[o1 + k + 1] + f];
            if (k     < n2) t20 = hs[s_bin[o2 + k]     + f];
            if (k + 1 < n2) t21 = hs[s_bin[o2 + k + 1] + f];
            if (k     < n3) t30 = hs[s_bin[o3 + k]     + f];
            if (k + 1 < n3) t31 = hs[s_bin[o3 + k + 1] + f];
            a0 += t00 + t01;
            a1 += t10 + t11;
            a2 += t20 + t21;
            a3 += t30 + t31;
        }
    } else {
        // fallback: direct global walk -- correctness safety net
        const unsigned int* p0 = bin + base + r0;
        const unsigned int* p1 = bin + base + r1;
        const unsigned int* p2 = bin + base + r2;
        const unsigned int* p3 = bin + base + r3;
#pragma unroll 2
        for (int k = 0; k < m; ++k) {
            if (k < n0) a0 += hs[p0[k] + f];
            if (k < n1) a1 += hs[p1[k] + f];
            if (k < n2) a2 += hs[p2[k] + f];
            if (k < n3) a3 += hs[p3[k] + f];
        }
    }
    int node0 = (b << BSHIFT) + (Q << 7) + dd0;
    if (node0 + 0 < N_NODES) unsafeAtomicAdd(&accG[((node0 + 0) << 4) + f], a0);
    if (node0 + 1 < N_NODES) unsafeAtomicAdd(&accG[((node0 + 1) << 4) + f], a1);
    if (node0 + 2 < N_NODES) unsafeAtomicAdd(&accG[((node0 + 2) << 4) + f], a2);
    if (node0 + 3 < N_NODES) unsafeAtomicAdd(&accG[((node0 + 3) << 4) + f], a3);
}

// out = dinv*(accG + hs_self) + bias, in place (accG aliases d_out).
template <int F, bool RELU>
__global__ void k_finish(float* __restrict__ B, float* __restrict__ accG,
                         const float* __restrict__ dinv,
                         const float* __restrict__ bias, float* __restrict__ out) {
    int i = blockIdx.x * blockDim.x + threadIdx.x;
    if (i >= N_NODES * 16) return;
    int node = i >> 4, ff = i & 15;
    float di = dinv[node];
    if (ff < F) {
        float r = di * (accG[i] + B[i]) + bias[ff];
        if (RELU) r = fmaxf(r, 0.f);
        out[node * 16 + ff] = r;
    }
}

extern "C" void kernel_launch(void* const* d_in, const int* in_sizes, int n_in,
                              void* d_out, int out_size, void* d_ws, size_t ws_size,
                              hipStream_t stream) {
    const float* x  = (const float*)d_in[0];
    const void*  ei = d_in[1];
    const float* W1 = (const float*)d_in[2];
    const float* b1 = (const float*)d_in[3];
    const float* W2 = (const float*)d_in[4];
    const float* b2 = (const float*)d_in[5];
    const float* W3 = (const float*)d_in[6];
    const float* b3 = (const float*)d_in[7];
    float* out = (float*)d_out;

    char* w = (char*)d_ws;
    int*   bucketCursor = (int*)(w + 0);        //    2048 B
    int*   flag         = (int*)(w + 2048);     //      64 B
    float* dinv         = (float*)(w + 2112);   //  800000 B
    unsigned short* seg16 = (unsigned short*)(w + 802112); // 391*2052*2 = 1604664 B
    unsigned int* bin   = (unsigned int*)(w + 2406784);    // 391*18432*4 = 28827648 B
    float* B            = (float*)(w + 31234432);          // 12800000 B (N*16)
    float* accG         = out;                  // d_out doubles as accumulator
    // total ws use ~44.0 MB (proven budget: 48.8 MB in R2)

    // ---- zero accumulator + build (q,dst)-sorted fixed-slot buckets ----
    k_zero<<<12500, 256, 0, stream>>>((int*)accG, N_NODES * 16);
    k_iota<<<1, 512, 0, stream>>>(bucketCursor);
    k_detect<<<1, 256, 0, stream>>>((const unsigned int*)ei, flag);
    k_binscatter<<<NCHUNK, 1024, 0, stream>>>(ei, flag, bucketCursor, bin);
    k_bucketsort<<<NBUCK, 1024, 0, stream>>>(bucketCursor, bin, dinv, seg16);

    // ---- layer 1 ----
    k_xw<11, 11, 11><<<782, 256, 0, stream>>>(x, W1, dinv, B);
    k_agg<<<NBUCK * 16, 512, 0, stream>>>(seg16, bin, B, accG);
    // ---- boundary 1: finish L1 + xw L2 (re-zeros accG) ----
    k_fx<11, 11><<<782, 256, 0, stream>>>(B, accG, dinv, b1, W2);
    // ---- layer 2 ----
    k_agg<<<NBUCK * 16, 512, 0, stream>>>(seg16, bin, B, accG);
    // ---- boundary 2: finish L2 + xw L3 (re-zeros accG) ----
    k_fx<11, 16><<<782, 256, 0, stream>>>(B, accG, dinv, b2, W3);
    // ---- layer 3 ----
    k_agg<<<NBUCK * 16, 512, 0, stream>>>(seg16, bin, B, accG);
    k_finish<16, false><<<12500, 256, 0, stream>>>(B, accG, dinv, b3, out);
}